// Round 7
// baseline (351.476 us; speedup 1.0000x reference)
//
#include <hip/hip_runtime.h>
#include <hip/hip_bf16.h>

#define NN 100000
#define NE 800000
#define DIM 96
#define NEG_SLOPE 0.01f
#define SCAN_BLOCKS ((NN + 255) / 256)   // 391

typedef short bf16x8 __attribute__((ext_vector_type(8)));
typedef float f32x4  __attribute__((ext_vector_type(4)));

__device__ __forceinline__ unsigned short f32_to_bf16_rne(float f) {
    unsigned int u = __float_as_uint(f);
    unsigned int r = (u + 0x7FFFu + ((u >> 16) & 1u)) >> 16;
    return (unsigned short)r;
}
__device__ __forceinline__ float bf16lo_to_f32(unsigned int u) { return __uint_as_float(u << 16); }
__device__ __forceinline__ float bf16hi_to_f32(unsigned int u) { return __uint_as_float(u & 0xFFFF0000u); }

// ---------------- CSR build ----------------

__global__ __launch_bounds__(256) void hist_kernel(const int* __restrict__ src, int* __restrict__ deg) {
    int e = blockIdx.x * 256 + threadIdx.x;
    if (e < NE) atomicAdd(&deg[src[e]], 1);
}

__global__ __launch_bounds__(256) void partial_kernel(const int* __restrict__ deg, int* __restrict__ blocksum) {
    __shared__ int lds[4];
    int idx = blockIdx.x * 256 + threadIdx.x;
    int v = (idx < NN) ? deg[idx] : 0;
    for (int off = 32; off > 0; off >>= 1) v += __shfl_down(v, off);
    int wave = threadIdx.x >> 6;
    int lane = threadIdx.x & 63;
    if (lane == 0) lds[wave] = v;
    __syncthreads();
    if (threadIdx.x == 0) blocksum[blockIdx.x] = lds[0] + lds[1] + lds[2] + lds[3];
}

__global__ __launch_bounds__(512) void scan_partials_kernel(const int* __restrict__ blocksum, int* __restrict__ blockoff) {
    __shared__ int lds[512];
    int i = threadIdx.x;
    int v = (i < SCAN_BLOCKS) ? blocksum[i] : 0;
    lds[i] = v;
    __syncthreads();
    for (int off = 1; off < 512; off <<= 1) {
        int t = (i >= off) ? lds[i - off] : 0;
        __syncthreads();
        lds[i] += t;
        __syncthreads();
    }
    if (i < SCAN_BLOCKS) blockoff[i] = lds[i] - v;
}

__global__ __launch_bounds__(256) void rowptr_kernel(const int* __restrict__ deg, const int* __restrict__ blockoff,
                                                     int* __restrict__ row_ptr, int* __restrict__ cursor) {
    __shared__ int lds[256];
    int i = threadIdx.x;
    int idx = blockIdx.x * 256 + i;
    int v = (idx < NN) ? deg[idx] : 0;
    lds[i] = v;
    __syncthreads();
    for (int off = 1; off < 256; off <<= 1) {
        int t = (i >= off) ? lds[i - off] : 0;
        __syncthreads();
        lds[i] += t;
        __syncthreads();
    }
    if (idx < NN) {
        int r = blockoff[blockIdx.x] + lds[i] - v;
        row_ptr[idx] = r;
        cursor[idx]  = r;
    }
    if (idx == 0) row_ptr[NN] = NE;
}

__global__ __launch_bounds__(256) void fill_kernel(const int* __restrict__ src, const int* __restrict__ dst,
                                                   int* __restrict__ cursor, int* __restrict__ dst_perm) {
    int e = blockIdx.x * 256 + threadIdx.x;
    if (e < NE) {
        int s = src[e];
        int pos = atomicAdd(&cursor[s], 1);
        dst_perm[pos] = dst[e];
    }
}

// ---------------- W convert: both weights fp32 [k][n] -> bf16 transposed [n][k] ----------------

__global__ __launch_bounds__(256) void convw_kernel(const float* __restrict__ W1, unsigned short* __restrict__ Wt1,
                                                    const float* __restrict__ W2, unsigned short* __restrict__ Wt2) {
    int idx = blockIdx.x * 256 + threadIdx.x;   // 2*9216
    if (idx < DIM * DIM) {
        int n = idx / DIM, k = idx % DIM;
        Wt1[n * DIM + k] = f32_to_bf16_rne(W1[k * DIM + n]);
    } else if (idx < 2 * DIM * DIM) {
        int j = idx - DIM * DIM;
        int n = j / DIM, k = j % DIM;
        Wt2[n * DIM + k] = f32_to_bf16_rne(W2[k * DIM + n]);
    }
}

// ---------------- MFMA GEMM + fused dots ----------------
// H = A @ W (bf16 out, split rows: Hlo[n][64], Hhi[n][32]); ssrc/sdst fused.
// 256 thr = 4 waves; wave: 16 rows x 96 cols = 6 n-tiles x 3 k-chunks of 16x16x32.

template <bool A_BF16>
__global__ __launch_bounds__(256) void gemm_mfma_kernel(const void* __restrict__ Alo_,
                                                        const void* __restrict__ Ahi_,
                                                        const unsigned short* __restrict__ Wt,
                                                        const float* __restrict__ avec,
                                                        unsigned short* __restrict__ Hlo,
                                                        unsigned short* __restrict__ Hhi,
                                                        float* __restrict__ ssrc, float* __restrict__ sdst,
                                                        int n) {
    const int wave = threadIdx.x >> 6;
    const int lane = threadIdx.x & 63;
    const int quad = lane >> 4;        // 0..3
    const int l16  = lane & 15;
    const int R0   = blockIdx.x * 64 + wave * 16;

    bf16x8 bfr[6][3];
#pragma unroll
    for (int nt = 0; nt < 6; nt++) {
        const unsigned short* wrow = Wt + (size_t)(nt * 16 + l16) * DIM;
#pragma unroll
        for (int kc = 0; kc < 3; kc++) bfr[nt][kc] = *(const bf16x8*)(wrow + kc * 32 + quad * 8);
    }

    int arow = R0 + l16;
    if (arow >= n) arow = n - 1;                 // clamp; stores guarded
    bf16x8 afr[3];
    if (A_BF16) {
        const unsigned short* alo = (const unsigned short*)Alo_ + (size_t)arow * 64;
        const unsigned short* ahi = (const unsigned short*)Ahi_ + (size_t)arow * 32;
        afr[0] = *(const bf16x8*)(alo + quad * 8);
        afr[1] = *(const bf16x8*)(alo + 32 + quad * 8);
        afr[2] = *(const bf16x8*)(ahi + quad * 8);
    } else {
        const float* ap = (const float*)Alo_ + (size_t)arow * DIM;
#pragma unroll
        for (int kc = 0; kc < 3; kc++) {
            float4 lo = *(const float4*)(ap + kc * 32 + quad * 8);
            float4 hi = *(const float4*)(ap + kc * 32 + quad * 8 + 4);
            union { bf16x8 v; unsigned short u[8]; } t;
            t.u[0] = f32_to_bf16_rne(lo.x); t.u[1] = f32_to_bf16_rne(lo.y);
            t.u[2] = f32_to_bf16_rne(lo.z); t.u[3] = f32_to_bf16_rne(lo.w);
            t.u[4] = f32_to_bf16_rne(hi.x); t.u[5] = f32_to_bf16_rne(hi.y);
            t.u[6] = f32_to_bf16_rne(hi.z); t.u[7] = f32_to_bf16_rne(hi.w);
            afr[kc] = t.v;
        }
    }

    f32x4 acc[6];
#pragma unroll
    for (int nt = 0; nt < 6; nt++) acc[nt] = (f32x4){0.f, 0.f, 0.f, 0.f};
#pragma unroll
    for (int kc = 0; kc < 3; kc++)
#pragma unroll
        for (int nt = 0; nt < 6; nt++)
            acc[nt] = __builtin_amdgcn_mfma_f32_16x16x32_bf16(afr[kc], bfr[nt][kc], acc[nt], 0, 0, 0);

    // ---- fused dots ----
    float as_[6], ad_[6];
#pragma unroll
    for (int nt = 0; nt < 6; nt++) {
        as_[nt] = avec[nt * 16 + l16];
        ad_[nt] = avec[96 + nt * 16 + l16];
    }
    float ps[4], pd[4];
#pragma unroll
    for (int r = 0; r < 4; r++) {
        float s = 0.f, d = 0.f;
#pragma unroll
        for (int nt = 0; nt < 6; nt++) {
            s = fmaf(acc[nt][r], as_[nt], s);
            d = fmaf(acc[nt][r], ad_[nt], d);
        }
        ps[r] = s; pd[r] = d;
    }
#pragma unroll
    for (int m = 1; m < 16; m <<= 1) {
#pragma unroll
        for (int r = 0; r < 4; r++) {
            ps[r] += __shfl_xor(ps[r], m);
            pd[r] += __shfl_xor(pd[r], m);
        }
    }
    {
        float psel = (l16 == 0) ? ps[0] : (l16 == 1) ? ps[1] : (l16 == 2) ? ps[2] : ps[3];
        float dsel = (l16 == 8) ? pd[0] : (l16 == 9) ? pd[1] : (l16 == 10) ? pd[2] : pd[3];
        int rs = R0 + quad * 4 + l16;
        int rd = R0 + quad * 4 + (l16 - 8);
        if (l16 < 4 && rs < n) ssrc[rs] = psel;
        if (l16 >= 8 && l16 < 12 && rd < n) sdst[rd] = dsel;
    }

    // ---- store H split bf16: row = R0+quad*4+r, col = nt*16+l16 ----
#pragma unroll
    for (int r = 0; r < 4; r++) {
        int orow = R0 + quad * 4 + r;
        if (orow < n) {
            unsigned short* lrow = Hlo + (size_t)orow * 64;
            unsigned short* hrow = Hhi + (size_t)orow * 32;
#pragma unroll
            for (int nt = 0; nt < 6; nt++) {
                int col = nt * 16 + l16;
                unsigned short v = f32_to_bf16_rne(acc[nt][r]);
                if (col < 64) lrow[col] = v; else hrow[col - 64] = v;
            }
        }
    }
}

// ---------------- fused CSR aggregation (edge weight computed inline) ----------------
// one wave per node; lanes 0..31 gather h_lo (1 aligned 128B line), lanes 32..47 gather h_hi (64B).

template <bool RELU, bool OUT_BF16>
__global__ __launch_bounds__(256) void agg_kernel(const unsigned short* __restrict__ hlo,
                                                  const unsigned short* __restrict__ hhi,
                                                  const float* __restrict__ ssrc,
                                                  const float* __restrict__ sdst,
                                                  const int* __restrict__ row_ptr,
                                                  const int* __restrict__ dst_perm,
                                                  void* __restrict__ out_lo,
                                                  void* __restrict__ out_hi) {
    int gid  = blockIdx.x * 256 + threadIdx.x;
    int node = gid >> 6;
    int lane = threadIdx.x & 63;
    if (node >= NN) return;
    int start = row_ptr[node];
    int end   = row_ptr[node + 1];
    float ss  = ssrc[node];
    const bool isLo = lane < 32;
    const bool act  = lane < 48;
    float acc0 = 0.f, acc1 = 0.f, wsum = 0.f;

    int p = start;
    for (; p + 8 <= end; p += 8) {
        int d[8];
#pragma unroll
        for (int i = 0; i < 8; i++) d[i] = dst_perm[p + i];
        float sv[8];
#pragma unroll
        for (int i = 0; i < 8; i++) sv[i] = sdst[d[i]];
        unsigned int u[8];
        if (act) {
#pragma unroll
            for (int i = 0; i < 8; i++) {
                u[i] = isLo ? ((const unsigned int*)(hlo + (size_t)d[i] * 64))[lane]
                            : ((const unsigned int*)(hhi + (size_t)d[i] * 32))[lane - 32];
            }
        }
#pragma unroll
        for (int i = 0; i < 8; i++) {
            float s  = ss + sv[i];
            float lr = s > 0.f ? s : NEG_SLOPE * s;
            float w  = __expf(-lr);
            wsum += w;
            if (act) {
                acc0 = fmaf(w, bf16lo_to_f32(u[i]), acc0);
                acc1 = fmaf(w, bf16hi_to_f32(u[i]), acc1);
            }
        }
    }
    for (; p < end; p++) {
        int dd = dst_perm[p];
        float s  = ss + sdst[dd];
        float lr = s > 0.f ? s : NEG_SLOPE * s;
        float w  = __expf(-lr);
        wsum += w;
        if (act) {
            unsigned int u = isLo ? ((const unsigned int*)(hlo + (size_t)dd * 64))[lane]
                                  : ((const unsigned int*)(hhi + (size_t)dd * 32))[lane - 32];
            acc0 = fmaf(w, bf16lo_to_f32(u), acc0);
            acc1 = fmaf(w, bf16hi_to_f32(u), acc1);
        }
    }

    float inv = 1.f / wsum;
    float r0 = acc0 * inv;
    float r1 = acc1 * inv;
    if (RELU) { r0 = fmaxf(r0, 0.f); r1 = fmaxf(r1, 0.f); }
    if (act) {
        if (OUT_BF16) {
            unsigned int pk = (unsigned int)f32_to_bf16_rne(r0) | ((unsigned int)f32_to_bf16_rne(r1) << 16);
            if (isLo) ((unsigned int*)out_lo)[(size_t)node * 32 + lane] = pk;
            else      ((unsigned int*)out_hi)[(size_t)node * 16 + (lane - 32)] = pk;
        } else {
            // full fp32 rows: float2 index node*48 + lane (lo: cols 2l; hi: cols 64+2(l-32))
            ((float2*)out_lo)[(size_t)node * 48 + lane] = make_float2(r0, r1);
        }
    }
}

// ---------------- launch ----------------

extern "C" void kernel_launch(void* const* d_in, const int* in_sizes, int n_in,
                              void* d_out, int out_size, void* d_ws, size_t ws_size,
                              hipStream_t stream) {
    (void)in_sizes; (void)n_in; (void)out_size; (void)ws_size;
    const int*   edge_index = (const int*)d_in[0];
    const float* x  = (const float*)d_in[1];
    const float* W1 = (const float*)d_in[2];
    const float* a1 = (const float*)d_in[3];
    const float* W2 = (const float*)d_in[4];
    const float* a2 = (const float*)d_in[5];
    float* out = (float*)d_out;

    const int* src = edge_index;
    const int* dst = edge_index + NE;

    char* ws = (char*)d_ws;
    size_t off = 0;
    auto alloc = [&](size_t bytes) -> void* {
        void* p = ws + off;
        off += (bytes + 255) & ~(size_t)255;
        return p;
    };
    unsigned short* h1lo = (unsigned short*)alloc((size_t)NN * 64 * 2);   // gemm out (both layers)
    unsigned short* h1hi = (unsigned short*)alloc((size_t)NN * 32 * 2);
    unsigned short* h2lo = (unsigned short*)alloc((size_t)NN * 64 * 2);   // layer-1 agg out
    unsigned short* h2hi = (unsigned short*)alloc((size_t)NN * 32 * 2);
    float* ssrc      = (float*)alloc((size_t)NN * 4);
    float* sdst      = (float*)alloc((size_t)NN * 4);
    int*   deg       = (int*)alloc((size_t)NN * 4);
    int*   row_ptr   = (int*)alloc((size_t)(NN + 1) * 4);
    int*   cursor    = (int*)alloc((size_t)NN * 4);
    int*   dst_perm  = (int*)alloc((size_t)NE * 4);
    int*   blocksum  = (int*)alloc((size_t)SCAN_BLOCKS * 4);
    int*   blockoff  = (int*)alloc((size_t)SCAN_BLOCKS * 4);
    unsigned short* Wt1 = (unsigned short*)alloc((size_t)DIM * DIM * 2);
    unsigned short* Wt2 = (unsigned short*)alloc((size_t)DIM * DIM * 2);

    // ---- build CSR + W converts ----
    hipMemsetAsync(deg, 0, (size_t)NN * 4, stream);
    hist_kernel<<<(NE + 255) / 256, 256, 0, stream>>>(src, deg);
    partial_kernel<<<SCAN_BLOCKS, 256, 0, stream>>>(deg, blocksum);
    scan_partials_kernel<<<1, 512, 0, stream>>>(blocksum, blockoff);
    rowptr_kernel<<<SCAN_BLOCKS, 256, 0, stream>>>(deg, blockoff, row_ptr, cursor);
    fill_kernel<<<(NE + 255) / 256, 256, 0, stream>>>(src, dst, cursor, dst_perm);
    convw_kernel<<<(2 * DIM * DIM + 255) / 256, 256, 0, stream>>>(W1, Wt1, W2, Wt2);

    int gemm_grid   = (NN + 63) / 64;                 // 1563
    int wave_blocks = ((NN * 64) + 255) / 256;        // 25000

    // ---- layer 1 ----
    gemm_mfma_kernel<false><<<gemm_grid, 256, 0, stream>>>(x, nullptr, Wt1, a1, h1lo, h1hi, ssrc, sdst, NN);
    agg_kernel<false, true><<<wave_blocks, 256, 0, stream>>>(h1lo, h1hi, ssrc, sdst, row_ptr, dst_perm, h2lo, h2hi);

    // ---- layer 2 ----
    gemm_mfma_kernel<true><<<gemm_grid, 256, 0, stream>>>(h2lo, h2hi, Wt2, a2, h1lo, h1hi, ssrc, sdst, NN);
    agg_kernel<true, false><<<wave_blocks, 256, 0, stream>>>(h1lo, h1hi, ssrc, sdst, row_ptr, dst_perm, out, nullptr);
}

// Round 8
// 293.182 us; speedup vs baseline: 1.1988x; 1.1988x over previous
//
#include <hip/hip_runtime.h>
#include <hip/hip_bf16.h>

#define NN 100000
#define NE 800000
#define DIM 96
#define NEG_SLOPE 0.01f
#define SCAN_BLOCKS ((NN + 255) / 256)   // 391
#define EDGE_BLOCKS ((NE + 255) / 256)   // 3125
#define CONV_BLOCKS ((2 * DIM * DIM + 255) / 256)  // 72

typedef short bf16x8 __attribute__((ext_vector_type(8)));
typedef float f32x4  __attribute__((ext_vector_type(4)));

__device__ __forceinline__ unsigned short f32_to_bf16_rne(float f) {
    unsigned int u = __float_as_uint(f);
    unsigned int r = (u + 0x7FFFu + ((u >> 16) & 1u)) >> 16;
    return (unsigned short)r;
}
__device__ __forceinline__ float bf16lo_to_f32(unsigned int u) { return __uint_as_float(u << 16); }
__device__ __forceinline__ float bf16hi_to_f32(unsigned int u) { return __uint_as_float(u & 0xFFFF0000u); }

// ---------------- CSR build + W convert ----------------

// blocks [0, EDGE_BLOCKS): histogram; blocks [EDGE_BLOCKS, EDGE_BLOCKS+CONV_BLOCKS): W converts
__global__ __launch_bounds__(256) void hist_conv_kernel(const int* __restrict__ src, int* __restrict__ deg,
                                                        const float* __restrict__ W1, unsigned short* __restrict__ Wt1,
                                                        const float* __restrict__ W2, unsigned short* __restrict__ Wt2) {
    if (blockIdx.x < EDGE_BLOCKS) {
        int e = blockIdx.x * 256 + threadIdx.x;
        if (e < NE) atomicAdd(&deg[src[e]], 1);
    } else {
        int idx = (blockIdx.x - EDGE_BLOCKS) * 256 + threadIdx.x;
        if (idx < DIM * DIM) {
            int n = idx / DIM, k = idx % DIM;
            Wt1[n * DIM + k] = f32_to_bf16_rne(W1[k * DIM + n]);
        } else if (idx < 2 * DIM * DIM) {
            int j = idx - DIM * DIM;
            int n = j / DIM, k = j % DIM;
            Wt2[n * DIM + k] = f32_to_bf16_rne(W2[k * DIM + n]);
        }
    }
}

__global__ __launch_bounds__(256) void partial_kernel(const int* __restrict__ deg, int* __restrict__ blocksum) {
    __shared__ int lds[4];
    int idx = blockIdx.x * 256 + threadIdx.x;
    int v = (idx < NN) ? deg[idx] : 0;
    for (int off = 32; off > 0; off >>= 1) v += __shfl_down(v, off);
    int wave = threadIdx.x >> 6;
    int lane = threadIdx.x & 63;
    if (lane == 0) lds[wave] = v;
    __syncthreads();
    if (threadIdx.x == 0) blocksum[blockIdx.x] = lds[0] + lds[1] + lds[2] + lds[3];
}

__global__ __launch_bounds__(512) void scan_partials_kernel(const int* __restrict__ blocksum, int* __restrict__ blockoff) {
    __shared__ int lds[512];
    int i = threadIdx.x;
    int v = (i < SCAN_BLOCKS) ? blocksum[i] : 0;
    lds[i] = v;
    __syncthreads();
    for (int off = 1; off < 512; off <<= 1) {
        int t = (i >= off) ? lds[i - off] : 0;
        __syncthreads();
        lds[i] += t;
        __syncthreads();
    }
    if (i < SCAN_BLOCKS) blockoff[i] = lds[i] - v;
}

__global__ __launch_bounds__(256) void rowptr_kernel(const int* __restrict__ deg, const int* __restrict__ blockoff,
                                                     int* __restrict__ row_ptr, int* __restrict__ cursor) {
    __shared__ int lds[256];
    int i = threadIdx.x;
    int idx = blockIdx.x * 256 + i;
    int v = (idx < NN) ? deg[idx] : 0;
    lds[i] = v;
    __syncthreads();
    for (int off = 1; off < 256; off <<= 1) {
        int t = (i >= off) ? lds[i - off] : 0;
        __syncthreads();
        lds[i] += t;
        __syncthreads();
    }
    if (idx < NN) {
        int r = blockoff[blockIdx.x] + lds[i] - v;
        row_ptr[idx] = r;
        cursor[idx]  = r;
    }
    if (idx == 0) row_ptr[NN] = NE;
}

__global__ __launch_bounds__(256) void fill_kernel(const int* __restrict__ src, const int* __restrict__ dst,
                                                   int* __restrict__ cursor, int* __restrict__ dst_perm) {
    int e = blockIdx.x * 256 + threadIdx.x;
    if (e < NE) {
        int s = src[e];
        int pos = atomicAdd(&cursor[s], 1);
        dst_perm[pos] = dst[e];
    }
}

// ---------------- MFMA GEMM + fused dots ----------------
// H[N,96](bf16) = A @ W; ssrc/sdst fused in epilogue.
// 256 thr = 4 waves; wave: 16 rows x 96 cols = 6 n-tiles x 3 k-chunks of 16x16x32.

template <bool A_BF16>
__global__ __launch_bounds__(256) void gemm_mfma_kernel(const void* __restrict__ A_,
                                                        const unsigned short* __restrict__ Wt,
                                                        const float* __restrict__ avec,
                                                        unsigned short* __restrict__ Hout,
                                                        float* __restrict__ ssrc, float* __restrict__ sdst,
                                                        int n) {
    const int wave = threadIdx.x >> 6;
    const int lane = threadIdx.x & 63;
    const int quad = lane >> 4;        // 0..3
    const int l16  = lane & 15;
    const int R0   = blockIdx.x * 64 + wave * 16;

    bf16x8 bfr[6][3];
#pragma unroll
    for (int nt = 0; nt < 6; nt++) {
        const unsigned short* wrow = Wt + (size_t)(nt * 16 + l16) * DIM;
#pragma unroll
        for (int kc = 0; kc < 3; kc++) bfr[nt][kc] = *(const bf16x8*)(wrow + kc * 32 + quad * 8);
    }

    int arow = R0 + l16;
    if (arow >= n) arow = n - 1;                 // clamp; stores guarded
    bf16x8 afr[3];
    if (A_BF16) {
        const unsigned short* ap = (const unsigned short*)A_ + (size_t)arow * DIM;
#pragma unroll
        for (int kc = 0; kc < 3; kc++) afr[kc] = *(const bf16x8*)(ap + kc * 32 + quad * 8);
    } else {
        const float* ap = (const float*)A_ + (size_t)arow * DIM;
#pragma unroll
        for (int kc = 0; kc < 3; kc++) {
            float4 lo = *(const float4*)(ap + kc * 32 + quad * 8);
            float4 hi = *(const float4*)(ap + kc * 32 + quad * 8 + 4);
            union { bf16x8 v; unsigned short u[8]; } t;
            t.u[0] = f32_to_bf16_rne(lo.x); t.u[1] = f32_to_bf16_rne(lo.y);
            t.u[2] = f32_to_bf16_rne(lo.z); t.u[3] = f32_to_bf16_rne(lo.w);
            t.u[4] = f32_to_bf16_rne(hi.x); t.u[5] = f32_to_bf16_rne(hi.y);
            t.u[6] = f32_to_bf16_rne(hi.z); t.u[7] = f32_to_bf16_rne(hi.w);
            afr[kc] = t.v;
        }
    }

    f32x4 acc[6];
#pragma unroll
    for (int nt = 0; nt < 6; nt++) acc[nt] = (f32x4){0.f, 0.f, 0.f, 0.f};
#pragma unroll
    for (int kc = 0; kc < 3; kc++)
#pragma unroll
        for (int nt = 0; nt < 6; nt++)
            acc[nt] = __builtin_amdgcn_mfma_f32_16x16x32_bf16(afr[kc], bfr[nt][kc], acc[nt], 0, 0, 0);

    // ---- fused dots: per-row dot(C_row, a[:96]) and dot(C_row, a[96:]) ----
    float as_[6], ad_[6];
#pragma unroll
    for (int nt = 0; nt < 6; nt++) {
        as_[nt] = avec[nt * 16 + l16];
        ad_[nt] = avec[96 + nt * 16 + l16];
    }
    float ps[4], pd[4];
#pragma unroll
    for (int r = 0; r < 4; r++) {
        float s = 0.f, d = 0.f;
#pragma unroll
        for (int nt = 0; nt < 6; nt++) {
            s = fmaf(acc[nt][r], as_[nt], s);
            d = fmaf(acc[nt][r], ad_[nt], d);
        }
        ps[r] = s; pd[r] = d;
    }
#pragma unroll
    for (int m = 1; m < 16; m <<= 1) {
#pragma unroll
        for (int r = 0; r < 4; r++) {
            ps[r] += __shfl_xor(ps[r], m);
            pd[r] += __shfl_xor(pd[r], m);
        }
    }
    {
        float psel = (l16 == 0) ? ps[0] : (l16 == 1) ? ps[1] : (l16 == 2) ? ps[2] : ps[3];
        float dsel = (l16 == 8) ? pd[0] : (l16 == 9) ? pd[1] : (l16 == 10) ? pd[2] : pd[3];
        int rs = R0 + quad * 4 + l16;
        int rd = R0 + quad * 4 + (l16 - 8);
        if (l16 < 4 && rs < n) ssrc[rs] = psel;
        if (l16 >= 8 && l16 < 12 && rd < n) sdst[rd] = dsel;
    }

    // ---- store H bf16: row = R0+quad*4+r, col = nt*16+l16 ----
#pragma unroll
    for (int r = 0; r < 4; r++) {
        int orow = R0 + quad * 4 + r;
        if (orow < n) {
            unsigned short* hrow = Hout + (size_t)orow * DIM;
#pragma unroll
            for (int nt = 0; nt < 6; nt++) hrow[nt * 16 + l16] = f32_to_bf16_rne(acc[nt][r]);
        }
    }
}

// ---------------- fused CSR aggregation ----------------
// one wave per node. Batch of 8 edges: lanes 0..7 compute the 8 edge weights
// (1 sdst gather + 1 exp per EDGE, not per lane); all lanes get w via shfl.
// h-gathers (lanes 0..47, uint = 2 bf16) are independent of w -> overlap the exp chain.
// Tail: predicated within the same constant-8 batch (waste lanes re-read edge p's row, L1-hit).

template <bool RELU, bool OUT_BF16>
__global__ __launch_bounds__(256) void agg_kernel(const unsigned short* __restrict__ h,
                                                  const float* __restrict__ ssrc,
                                                  const float* __restrict__ sdst,
                                                  const int* __restrict__ row_ptr,
                                                  const int* __restrict__ dst_perm,
                                                  void* __restrict__ out) {
    int gid  = blockIdx.x * 256 + threadIdx.x;
    int node = gid >> 6;
    int lane = threadIdx.x & 63;
    if (node >= NN) return;
    int start = row_ptr[node];
    int end   = row_ptr[node + 1];
    float ss  = ssrc[node];
    const bool act = lane < 48;
    float acc0 = 0.f, acc1 = 0.f, wsum = 0.f;

    for (int p = start; p < end; p += 8) {
        const int cnt = min(8, end - p);
        int d[8];
#pragma unroll
        for (int i = 0; i < 8; i++) {
            int idx = p + i;
            d[i] = dst_perm[(idx < end) ? idx : p];
        }
        // lanes 0..7: one edge weight each
        float wl = 0.f;
        if (lane < cnt) {
            float s  = ss + sdst[d[lane]];
            float lr = s > 0.f ? s : NEG_SLOPE * s;
            wl = __expf(-lr);
        }
        unsigned int u[8];
        if (act) {
#pragma unroll
            for (int i = 0; i < 8; i++)
                u[i] = ((const unsigned int*)(h + (size_t)d[i] * DIM))[lane];
        }
#pragma unroll
        for (int i = 0; i < 8; i++) {
            float w = __shfl(wl, i);   // 0 for i >= cnt
            wsum += w;
            if (act) {
                acc0 = fmaf(w, bf16lo_to_f32(u[i]), acc0);
                acc1 = fmaf(w, bf16hi_to_f32(u[i]), acc1);
            }
        }
    }

    float inv = 1.f / wsum;
    float r0 = acc0 * inv;
    float r1 = acc1 * inv;
    if (RELU) { r0 = fmaxf(r0, 0.f); r1 = fmaxf(r1, 0.f); }
    if (act) {
        if (OUT_BF16) {
            unsigned int pk = (unsigned int)f32_to_bf16_rne(r0) | ((unsigned int)f32_to_bf16_rne(r1) << 16);
            ((unsigned int*)out)[(size_t)node * 48 + lane] = pk;
        } else {
            ((float2*)out)[(size_t)node * 48 + lane] = make_float2(r0, r1);
        }
    }
}

// ---------------- launch ----------------

extern "C" void kernel_launch(void* const* d_in, const int* in_sizes, int n_in,
                              void* d_out, int out_size, void* d_ws, size_t ws_size,
                              hipStream_t stream) {
    (void)in_sizes; (void)n_in; (void)out_size; (void)ws_size;
    const int*   edge_index = (const int*)d_in[0];
    const float* x  = (const float*)d_in[1];
    const float* W1 = (const float*)d_in[2];
    const float* a1 = (const float*)d_in[3];
    const float* W2 = (const float*)d_in[4];
    const float* a2 = (const float*)d_in[5];
    float* out = (float*)d_out;

    const int* src = edge_index;
    const int* dst = edge_index + NE;

    char* ws = (char*)d_ws;
    size_t off = 0;
    auto alloc = [&](size_t bytes) -> void* {
        void* p = ws + off;
        off += (bytes + 255) & ~(size_t)255;
        return p;
    };
    unsigned short* h1 = (unsigned short*)alloc((size_t)NN * DIM * 2);   // gemm out (both layers)
    unsigned short* h2 = (unsigned short*)alloc((size_t)NN * DIM * 2);   // layer-1 agg out
    float* ssrc      = (float*)alloc((size_t)NN * 4);
    float* sdst      = (float*)alloc((size_t)NN * 4);
    int*   deg       = (int*)alloc((size_t)NN * 4);
    int*   row_ptr   = (int*)alloc((size_t)(NN + 1) * 4);
    int*   cursor    = (int*)alloc((size_t)NN * 4);
    int*   dst_perm  = (int*)alloc((size_t)NE * 4);
    int*   blocksum  = (int*)alloc((size_t)SCAN_BLOCKS * 4);
    int*   blockoff  = (int*)alloc((size_t)SCAN_BLOCKS * 4);
    unsigned short* Wt1 = (unsigned short*)alloc((size_t)DIM * DIM * 2);
    unsigned short* Wt2 = (unsigned short*)alloc((size_t)DIM * DIM * 2);

    // ---- build CSR + W converts ----
    hipMemsetAsync(deg, 0, (size_t)NN * 4, stream);
    hist_conv_kernel<<<EDGE_BLOCKS + CONV_BLOCKS, 256, 0, stream>>>(src, deg, W1, Wt1, W2, Wt2);
    partial_kernel<<<SCAN_BLOCKS, 256, 0, stream>>>(deg, blocksum);
    scan_partials_kernel<<<1, 512, 0, stream>>>(blocksum, blockoff);
    rowptr_kernel<<<SCAN_BLOCKS, 256, 0, stream>>>(deg, blockoff, row_ptr, cursor);
    fill_kernel<<<EDGE_BLOCKS, 256, 0, stream>>>(src, dst, cursor, dst_perm);

    int gemm_grid   = (NN + 63) / 64;                 // 1563
    int wave_blocks = ((NN * 64) + 255) / 256;        // 25000

    // ---- layer 1 ----
    gemm_mfma_kernel<false><<<gemm_grid, 256, 0, stream>>>(x, Wt1, a1, h1, ssrc, sdst, NN);
    agg_kernel<false, true><<<wave_blocks, 256, 0, stream>>>(h1, ssrc, sdst, row_ptr, dst_perm, h2);

    // ---- layer 2 ----
    gemm_mfma_kernel<true><<<gemm_grid, 256, 0, stream>>>(h2, Wt2, a2, h1, ssrc, sdst, NN);
    agg_kernel<true, false><<<wave_blocks, 256, 0, stream>>>(h1, ssrc, sdst, row_ptr, dst_perm, out);
}